// Round 6
// baseline (498.665 us; speedup 1.0000x reference)
//
#include <hip/hip_runtime.h>
#include <hip/hip_bf16.h>

#define NN 100000
#define NE 1600000
#define CIN 64
#define HIDN 32
#define NG 128
#define SLOPE 0.01f

// ---------------- CSR build: one atomic pass producing u8 ranks ----------------
// 8 edges per thread: 8 outstanding atomics. deg ~ Poisson(16) -> rank < 256 always.

__global__ __launch_bounds__(256) void k_rank(const int* __restrict__ dst,
                                              int* __restrict__ deg,
                                              unsigned int* __restrict__ rank) {
  int i = blockIdx.x * 256 + threadIdx.x;  // oct-edge index
  if (i * 8 >= NE) return;
  int4 a = ((const int4*)dst)[2 * i];
  int4 b = ((const int4*)dst)[2 * i + 1];
  unsigned int r0 = atomicAdd(&deg[a.x], 1);
  unsigned int r1 = atomicAdd(&deg[a.y], 1);
  unsigned int r2 = atomicAdd(&deg[a.z], 1);
  unsigned int r3 = atomicAdd(&deg[a.w], 1);
  unsigned int r4 = atomicAdd(&deg[b.x], 1);
  unsigned int r5 = atomicAdd(&deg[b.y], 1);
  unsigned int r6 = atomicAdd(&deg[b.z], 1);
  unsigned int r7 = atomicAdd(&deg[b.w], 1);
  uint2 packed;
  packed.x = r0 | (r1 << 8) | (r2 << 16) | (r3 << 24);
  packed.y = r4 | (r5 << 8) | (r6 << 16) | (r7 << 24);
  ((uint2*)rank)[i] = packed;
}

// ---------------- prefix scan (3-kernel), 1024 items/block ----------------

__global__ __launch_bounds__(256) void k_scan1(const int* __restrict__ deg,
                                               int* __restrict__ bsum) {
  __shared__ int s[256];
  int t = threadIdx.x;
  int base = blockIdx.x * 1024 + t * 4;
  int sum = 0;
#pragma unroll
  for (int j = 0; j < 4; ++j) {
    int idx = base + j;
    if (idx < NN) sum += deg[idx];
  }
  s[t] = sum;
  __syncthreads();
  for (int o = 128; o > 0; o >>= 1) {
    if (t < o) s[t] += s[t + o];
    __syncthreads();
  }
  if (t == 0) bsum[blockIdx.x] = s[0];
}

// middle scan + group counts + zero the output pool, one block of 256
__global__ __launch_bounds__(256) void k_mid(int* __restrict__ bsum,
                                             int* __restrict__ rowp,
                                             const int* __restrict__ batch,
                                             float* __restrict__ cinv,
                                             float* __restrict__ out, int nblk) {
  __shared__ int s[128];
  __shared__ int sb[NG + 1];
  int t = threadIdx.x;
  if (t < nblk) s[t] = bsum[t];
  if (t <= NG) {
    int lo = 0, hi = NN;  // lower_bound of t in sorted batch
    while (lo < hi) {
      int mid = (lo + hi) >> 1;
      if (batch[mid] < t) lo = mid + 1; else hi = mid;
    }
    sb[t] = lo;
  }
  for (int i = t; i < NG * HIDN; i += 256) out[i] = 0.f;
  __syncthreads();
  if (t == 0) {
    int run = 0;
    for (int i = 0; i < nblk; ++i) {
      int v = s[i];
      s[i] = run;
      run += v;
    }
    rowp[NN] = run;  // == NE
  }
  __syncthreads();
  if (t < nblk) bsum[t] = s[t];
  if (t < NG) {
    int c = sb[t + 1] - sb[t];
    cinv[t] = 1.0f / (3.0f * fmaxf((float)c, 1.0f));
  }
}

// scan3 + dinv fused (deg values already in registers)
__global__ __launch_bounds__(256) void k_scan3(const int* __restrict__ deg,
                                               const int* __restrict__ bsum,
                                               int* __restrict__ rowp,
                                               float* __restrict__ dinv) {
  __shared__ int s[256];
  int t = threadIdx.x;
  int base = blockIdx.x * 1024 + t * 4;
  int d0 = 0, d1 = 0, d2 = 0, d3 = 0;
  if (base < NN) d0 = deg[base];
  if (base + 1 < NN) d1 = deg[base + 1];
  if (base + 2 < NN) d2 = deg[base + 2];
  if (base + 3 < NN) d3 = deg[base + 3];
  int ts = d0 + d1 + d2 + d3;
  s[t] = ts;
  __syncthreads();
  for (int o = 1; o < 256; o <<= 1) {
    int v = (t >= o) ? s[t - o] : 0;
    __syncthreads();
    s[t] += v;
    __syncthreads();
  }
  int run = bsum[blockIdx.x] + s[t] - ts;  // exclusive prefix for this thread
  if (base < NN) { rowp[base] = run; dinv[base] = rsqrtf((float)d0 + 1.0f); run += d0; }
  if (base + 1 < NN) { rowp[base + 1] = run; dinv[base + 1] = rsqrtf((float)d1 + 1.0f); run += d1; }
  if (base + 2 < NN) { rowp[base + 2] = run; dinv[base + 2] = rsqrtf((float)d2 + 1.0f); run += d2; }
  if (base + 3 < NN) { rowp[base + 3] = run; dinv[base + 3] = rsqrtf((float)d3 + 1.0f); run += d3; }
}

// no atomics: position = rowp[dst] + u8 rank; 8 edges per thread
__global__ __launch_bounds__(256) void k_scatter(const int* __restrict__ src,
                                                 const int* __restrict__ dst,
                                                 const unsigned int* __restrict__ rank,
                                                 const int* __restrict__ rowp,
                                                 int* __restrict__ col) {
  int i = blockIdx.x * 256 + threadIdx.x;  // oct-edge index
  if (i * 8 >= NE) return;
  int4 da = ((const int4*)dst)[2 * i];
  int4 db = ((const int4*)dst)[2 * i + 1];
  uint2 rr = ((const uint2*)rank)[i];
  int4 sa = ((const int4*)src)[2 * i];
  int4 sb = ((const int4*)src)[2 * i + 1];
  int p0 = rowp[da.x] + (int)(rr.x & 0xff);
  int p1 = rowp[da.y] + (int)((rr.x >> 8) & 0xff);
  int p2 = rowp[da.z] + (int)((rr.x >> 16) & 0xff);
  int p3 = rowp[da.w] + (int)(rr.x >> 24);
  int p4 = rowp[db.x] + (int)(rr.y & 0xff);
  int p5 = rowp[db.y] + (int)((rr.y >> 8) & 0xff);
  int p6 = rowp[db.z] + (int)((rr.y >> 16) & 0xff);
  int p7 = rowp[db.w] + (int)(rr.y >> 24);
  col[p0] = sa.x; col[p1] = sa.y; col[p2] = sa.z; col[p3] = sa.w;
  col[p4] = sb.x; col[p5] = sb.y; col[p6] = sb.z; col[p7] = sb.w;
}

// ---------------- dense hs = bf16( dinv ⊙ (in @ W) ) ----------------

template <int K>
__global__ __launch_bounds__(256) void k_mm(const float* __restrict__ in,
                                            const float* __restrict__ W,
                                            const float* __restrict__ dinv,
                                            __hip_bfloat16* __restrict__ out) {
  __shared__ float sW[K * HIDN];
  int t = threadIdx.x;
  for (int i = t; i < K * HIDN; i += 256) sW[i] = W[i];
  __syncthreads();
  int gid = blockIdx.x * 256 + t;
  int node = gid >> 5;
  int f = gid & 31;
  if (node >= NN) return;
  const float* xr = in + node * K;
  float acc = 0.f;
#pragma unroll
  for (int k = 0; k < K; ++k) acc += xr[k] * sW[k * HIDN + f];
  out[node * HIDN + f] = __float2bfloat16(acc * dinv[node]);
}

// ---------------- flat segmented CSR aggregation + fused epilogue ----------------
// Block owns 32 nodes = one contiguous edge range [rowp[base], rowp[base+32]).
// 8 subs x 32 features; each sub takes 1/8 of the edges (uniform), accumulating
// per-node partials into LDS part[32][32] (conflict-free ds_add_f32).
// No per-row pipeline drains; sustained unroll-8 gather stream.

template <int WRITE_H>
__global__ __launch_bounds__(256) void k_agg(const __hip_bfloat16* __restrict__ hs,
                                             const int* __restrict__ rowp,
                                             const int* __restrict__ col,
                                             const float* __restrict__ dinv,
                                             const int* __restrict__ batch,
                                             const float* __restrict__ cinv,
                                             const float* __restrict__ bias,
                                             float* __restrict__ hout,
                                             float* __restrict__ pool) {
  __shared__ float part[32][32];
  __shared__ int srow[33];
  const int t = threadIdx.x;
  const int f = t & 31;
  const int sub = t >> 5;  // 0..7
  const int base = blockIdx.x * 32;

  ((float4*)part)[t] = float4{0.f, 0.f, 0.f, 0.f};
  if (t < 33) srow[t] = rowp[base + t];  // base+32 <= NN (NN % 32 == 0)
  __syncthreads();

  const int rs0 = srow[0];
  const int T = srow[32] - rs0;
  int e = rs0 + (T * sub) / 8;
  const int eE = rs0 + (T * (sub + 1)) / 8;

  // locate starting node j: srow[j] <= e < srow[j+1]
  int j;
  {
    int lo = 0, hi = 32;
    while (lo < hi) {
      int mid = (lo + hi) >> 1;
      if (srow[mid + 1] <= e) lo = mid + 1; else hi = mid;
    }
    j = lo;
  }

  float acc = 0.f;
  while (e < eE) {
    const int rend = srow[j + 1];
    const int nb = rend < eE ? rend : eE;
    while (nb - e >= 8) {
      const int c0 = col[e], c1 = col[e + 1], c2 = col[e + 2], c3 = col[e + 3];
      const int c4 = col[e + 4], c5 = col[e + 5], c6 = col[e + 6], c7 = col[e + 7];
      const float v0 = __bfloat162float(hs[c0 * HIDN + f]);
      const float v1 = __bfloat162float(hs[c1 * HIDN + f]);
      const float v2 = __bfloat162float(hs[c2 * HIDN + f]);
      const float v3 = __bfloat162float(hs[c3 * HIDN + f]);
      const float v4 = __bfloat162float(hs[c4 * HIDN + f]);
      const float v5 = __bfloat162float(hs[c5 * HIDN + f]);
      const float v6 = __bfloat162float(hs[c6 * HIDN + f]);
      const float v7 = __bfloat162float(hs[c7 * HIDN + f]);
      acc += ((v0 + v1) + (v2 + v3)) + ((v4 + v5) + (v6 + v7));
      e += 8;
    }
    while (e < nb) {
      acc += __bfloat162float(hs[col[e] * HIDN + f]);
      ++e;
    }
    atomicAdd(&part[j][f], acc);  // LDS, f spans 32 banks -> conflict-free
    acc = 0.f;
    if (nb == rend) ++j;
  }
  __syncthreads();

  // finalize: each thread handles 4 nodes (sub*4 + q), feature f
  const float bf = bias[f];
  float pacc = 0.f;
  int gcur = -1;
#pragma unroll
  for (int q = 0; q < 4; ++q) {
    const int li = sub * 4 + q;
    const int i = base + li;
    const float self = __bfloat162float(hs[i * HIDN + f]);
    float v = (part[li][f] + self) * dinv[i] + bf;
    v = v > 0.f ? v : SLOPE * v;
    if (WRITE_H) hout[i * HIDN + f] = v;
    const int g = batch[i];
    if (g != gcur) {
      if (gcur >= 0) unsafeAtomicAdd(&pool[gcur * HIDN + f], pacc * cinv[gcur]);
      gcur = g;
      pacc = 0.f;
    }
    pacc += v;
  }
  if (gcur >= 0) unsafeAtomicAdd(&pool[gcur * HIDN + f], pacc * cinv[gcur]);
}

// ---------------- launch ----------------

extern "C" void kernel_launch(void* const* d_in, const int* in_sizes, int n_in,
                              void* d_out, int out_size, void* d_ws, size_t ws_size,
                              hipStream_t stream) {
  const float* x = (const float*)d_in[0];
  const float* W0 = (const float*)d_in[1];
  const float* b0 = (const float*)d_in[2];
  const float* W1 = (const float*)d_in[3];
  const float* b1 = (const float*)d_in[4];
  const float* W2 = (const float*)d_in[5];
  const float* b2 = (const float*)d_in[6];
  const int* src = (const int*)d_in[7];
  const int* dst = (const int*)d_in[8];
  const int* batch = (const int*)d_in[9];
  float* out = (float*)d_out;

  char* ws = (char*)d_ws;
  auto carve = [&](size_t bytes) -> char* {
    char* p = ws;
    ws += (bytes + 255) & ~(size_t)255;
    return p;
  };
  int* deg = (int*)carve(NN * 4);
  unsigned int* rank = (unsigned int*)carve((size_t)NE);  // u8 per edge
  int* rowp = (int*)carve((NN + 1) * 4);
  int* bsum = (int*)carve(128 * 4);
  float* dinv = (float*)carve(NN * 4);
  float* cinv = (float*)carve(NG * 4);
  int* col = (int*)carve((size_t)NE * 4);
  float* hA = (float*)carve((size_t)NN * HIDN * 4);
  __hip_bfloat16* hs = (__hip_bfloat16*)carve((size_t)NN * HIDN * 2);

  hipMemsetAsync(deg, 0, NN * 4, stream);

  const int oct_grid = (NE / 8 + 255) / 256;  // 782
  k_rank<<<oct_grid, 256, 0, stream>>>(dst, deg, rank);

  int nblk = (NN + 1023) / 1024;  // 98
  k_scan1<<<nblk, 256, 0, stream>>>(deg, bsum);
  k_mid<<<1, 256, 0, stream>>>(bsum, rowp, batch, cinv, out, nblk);
  k_scan3<<<nblk, 256, 0, stream>>>(deg, bsum, rowp, dinv);

  k_scatter<<<oct_grid, 256, 0, stream>>>(src, dst, rank, rowp, col);

  const int mm_grid = (NN * HIDN + 255) / 256;  // 12500
  const int agg_grid = NN / 32;                 // 3125

  // layer 0
  k_mm<CIN><<<mm_grid, 256, 0, stream>>>(x, W0, dinv, hs);
  k_agg<1><<<agg_grid, 256, 0, stream>>>(hs, rowp, col, dinv, batch, cinv, b0, hA, out);
  // layer 1
  k_mm<HIDN><<<mm_grid, 256, 0, stream>>>(hA, W1, dinv, hs);
  k_agg<1><<<agg_grid, 256, 0, stream>>>(hs, rowp, col, dinv, batch, cinv, b1, hA, out);
  // layer 2 (pool only; hout never consumed)
  k_mm<HIDN><<<mm_grid, 256, 0, stream>>>(hA, W2, dinv, hs);
  k_agg<0><<<agg_grid, 256, 0, stream>>>(hs, rowp, col, dinv, batch, cinv, b2, hA, out);
}

// Round 7
// 439.487 us; speedup vs baseline: 1.1347x; 1.1347x over previous
//
#include <hip/hip_runtime.h>
#include <hip/hip_bf16.h>

#define NN 100000
#define NE 1600000
#define CIN 64
#define HIDN 32
#define NG 128
#define SLOPE 0.01f
#define NBLK 98           // (NN+1023)/1024
#define SCAT_BLOCKS 782   // ceil(NE/8/256)
#define MM0_BLOCKS 12500  // NN*HIDN/256
#define AGG_BLOCKS 3125   // NN/32

// ---------------- CSR build: one atomic pass producing u8 ranks ----------------

__global__ __launch_bounds__(256) void k_rank(const int* __restrict__ dst,
                                              int* __restrict__ deg,
                                              unsigned int* __restrict__ rank) {
  int i = blockIdx.x * 256 + threadIdx.x;  // oct-edge index
  if (i * 8 >= NE) return;
  int4 a = ((const int4*)dst)[2 * i];
  int4 b = ((const int4*)dst)[2 * i + 1];
  unsigned int r0 = atomicAdd(&deg[a.x], 1);
  unsigned int r1 = atomicAdd(&deg[a.y], 1);
  unsigned int r2 = atomicAdd(&deg[a.z], 1);
  unsigned int r3 = atomicAdd(&deg[a.w], 1);
  unsigned int r4 = atomicAdd(&deg[b.x], 1);
  unsigned int r5 = atomicAdd(&deg[b.y], 1);
  unsigned int r6 = atomicAdd(&deg[b.z], 1);
  unsigned int r7 = atomicAdd(&deg[b.w], 1);
  uint2 packed;
  packed.x = r0 | (r1 << 8) | (r2 << 16) | (r3 << 24);
  packed.y = r4 | (r5 << 8) | (r6 << 16) | (r7 << 24);
  ((uint2*)rank)[i] = packed;
}

// ---------------- scan1: block sums + dinv; block 0 also cinv + zero out ----------------

__global__ __launch_bounds__(256) void k_scan1(const int* __restrict__ deg,
                                               int* __restrict__ bsum,
                                               float* __restrict__ dinv,
                                               const int* __restrict__ batch,
                                               float* __restrict__ cinv,
                                               float* __restrict__ out) {
  __shared__ int s[256];
  __shared__ int sb[NG + 1];
  int t = threadIdx.x;
  int base = blockIdx.x * 1024 + t * 4;
  int sum = 0;
#pragma unroll
  for (int j = 0; j < 4; ++j) {
    int idx = base + j;
    if (idx < NN) {
      int d = deg[idx];
      sum += d;
      dinv[idx] = rsqrtf((float)d + 1.0f);
    }
  }
  s[t] = sum;
  __syncthreads();
  for (int o = 128; o > 0; o >>= 1) {
    if (t < o) s[t] += s[t + o];
    __syncthreads();
  }
  if (t == 0) bsum[blockIdx.x] = s[0];
  if (blockIdx.x == 0) {
    if (t <= NG) {
      int lo = 0, hi = NN;  // lower_bound of t in sorted batch
      while (lo < hi) {
        int mid = (lo + hi) >> 1;
        if (batch[mid] < t) lo = mid + 1; else hi = mid;
      }
      sb[t] = lo;
    }
    for (int i = t; i < NG * HIDN; i += 256) out[i] = 0.f;
    __syncthreads();
    if (t < NG) {
      int c = sb[t + 1] - sb[t];
      cinv[t] = 1.0f / (3.0f * fmaxf((float)c, 1.0f));
    }
  }
}

// ---------------- scan3: self-scan block sums + per-element rowp ----------------

__global__ __launch_bounds__(256) void k_scan3(const int* __restrict__ deg,
                                               const int* __restrict__ bsum,
                                               int* __restrict__ rowp) {
  __shared__ int s[256];
  __shared__ int sb2[128];
  int t = threadIdx.x;
  if (t < 128) sb2[t] = (t < NBLK) ? bsum[t] : 0;
  int base = blockIdx.x * 1024 + t * 4;
  int d0 = 0, d1 = 0, d2 = 0, d3 = 0;
  if (base < NN) d0 = deg[base];
  if (base + 1 < NN) d1 = deg[base + 1];
  if (base + 2 < NN) d2 = deg[base + 2];
  if (base + 3 < NN) d3 = deg[base + 3];
  int ts = d0 + d1 + d2 + d3;
  s[t] = ts;
  __syncthreads();
  // inclusive scan of the 98 block sums (128-wide Hillis)
  for (int o = 1; o < 128; o <<= 1) {
    int v = (t < 128 && t >= o) ? sb2[t - o] : 0;
    __syncthreads();
    if (t < 128) sb2[t] += v;
    __syncthreads();
  }
  // inclusive scan of the 256 thread sums
  for (int o = 1; o < 256; o <<= 1) {
    int v = (t >= o) ? s[t - o] : 0;
    __syncthreads();
    s[t] += v;
    __syncthreads();
  }
  int blockoff = blockIdx.x ? sb2[blockIdx.x - 1] : 0;
  int run = blockoff + s[t] - ts;  // exclusive prefix
  if (base < NN) { rowp[base] = run; run += d0; }
  if (base + 1 < NN) { rowp[base + 1] = run; run += d1; }
  if (base + 2 < NN) { rowp[base + 2] = run; run += d2; }
  if (base + 3 < NN) { rowp[base + 3] = run; run += d3; }
  if (blockIdx.x == NBLK - 1 && t == 255) rowp[NN] = run;  // == NE
}

// ---------------- scatter (blocks 0..781)  ∥  mm0 (blocks 782..) ----------------

__global__ __launch_bounds__(256) void k_sm(const int* __restrict__ src,
                                            const int* __restrict__ dst,
                                            const unsigned int* __restrict__ rank,
                                            const int* __restrict__ rowp,
                                            int* __restrict__ col,
                                            const float* __restrict__ x,
                                            const float* __restrict__ W0,
                                            const float* __restrict__ dinv,
                                            __hip_bfloat16* __restrict__ hs) {
  __shared__ float sW[CIN * HIDN];
  if (blockIdx.x < SCAT_BLOCKS) {
    int i = blockIdx.x * 256 + threadIdx.x;  // oct-edge index
    if (i * 8 >= NE) return;
    int4 da = ((const int4*)dst)[2 * i];
    int4 db = ((const int4*)dst)[2 * i + 1];
    uint2 rr = ((const uint2*)rank)[i];
    int4 sa = ((const int4*)src)[2 * i];
    int4 sb = ((const int4*)src)[2 * i + 1];
    col[rowp[da.x] + (int)(rr.x & 0xff)] = sa.x;
    col[rowp[da.y] + (int)((rr.x >> 8) & 0xff)] = sa.y;
    col[rowp[da.z] + (int)((rr.x >> 16) & 0xff)] = sa.z;
    col[rowp[da.w] + (int)(rr.x >> 24)] = sa.w;
    col[rowp[db.x] + (int)(rr.y & 0xff)] = sb.x;
    col[rowp[db.y] + (int)((rr.y >> 8) & 0xff)] = sb.y;
    col[rowp[db.z] + (int)((rr.y >> 16) & 0xff)] = sb.z;
    col[rowp[db.w] + (int)(rr.y >> 24)] = sb.w;
    return;
  }
  int t = threadIdx.x;
  for (int i = t; i < CIN * HIDN; i += 256) sW[i] = W0[i];
  __syncthreads();
  int gid = (blockIdx.x - SCAT_BLOCKS) * 256 + t;
  int node = gid >> 5;
  int f = gid & 31;
  const float* xr = x + node * CIN;
  float acc = 0.f;
#pragma unroll
  for (int k = 0; k < CIN; ++k) acc += xr[k] * sW[k * HIDN + f];
  hs[node * HIDN + f] = __float2bfloat16(acc * dinv[node]);
}

// ---------------- CSR aggregation + epilogue (+ optional fused next-layer mm) ----------------
// Round-5 per-row gather structure (proven 66us). hs pre-scaled by dinv.
// FUSE: stage v rows in LDS, then hs_next = bf16(dinv * (v @ Wn)) per thread
// using 32 W-column registers (W column f).

template <int FUSE>
__global__ __launch_bounds__(256) void k_agg(const __hip_bfloat16* __restrict__ hs,
                                             const int* __restrict__ rowp,
                                             const int* __restrict__ col,
                                             const float* __restrict__ dinv,
                                             const int* __restrict__ batch,
                                             const float* __restrict__ cinv,
                                             const float* __restrict__ bias,
                                             const float* __restrict__ Wn,
                                             __hip_bfloat16* __restrict__ hs_next,
                                             float* __restrict__ pool) {
  __shared__ float vrow[32][32];
  const int t = threadIdx.x;
  const int f = t & 31;
  const int sub = t >> 5;  // 0..7
  const int base = blockIdx.x * 32;

  float wreg[HIDN];
  if (FUSE) {
#pragma unroll
    for (int k = 0; k < HIDN; ++k) wreg[k] = Wn[k * HIDN + f];
  }

  const float bf = bias[f];
  float pacc = 0.f;
  int gcur = -1;
#pragma unroll
  for (int it = 0; it < 4; ++it) {
    const int i = base + it * 8 + sub;  // always < NN (NN % 32 == 0)
    float acc = __bfloat162float(hs[i * HIDN + f]);  // self-loop term
    const int rs = rowp[i];
    const int re = rowp[i + 1];
    int e = rs;
    for (; e + 8 <= re; e += 8) {
      const int c0 = __builtin_nontemporal_load(col + e);
      const int c1 = __builtin_nontemporal_load(col + e + 1);
      const int c2 = __builtin_nontemporal_load(col + e + 2);
      const int c3 = __builtin_nontemporal_load(col + e + 3);
      const int c4 = __builtin_nontemporal_load(col + e + 4);
      const int c5 = __builtin_nontemporal_load(col + e + 5);
      const int c6 = __builtin_nontemporal_load(col + e + 6);
      const int c7 = __builtin_nontemporal_load(col + e + 7);
      const float v0 = __bfloat162float(hs[c0 * HIDN + f]);
      const float v1 = __bfloat162float(hs[c1 * HIDN + f]);
      const float v2 = __bfloat162float(hs[c2 * HIDN + f]);
      const float v3 = __bfloat162float(hs[c3 * HIDN + f]);
      const float v4 = __bfloat162float(hs[c4 * HIDN + f]);
      const float v5 = __bfloat162float(hs[c5 * HIDN + f]);
      const float v6 = __bfloat162float(hs[c6 * HIDN + f]);
      const float v7 = __bfloat162float(hs[c7 * HIDN + f]);
      acc += ((v0 + v1) + (v2 + v3)) + ((v4 + v5) + (v6 + v7));
    }
    for (; e + 4 <= re; e += 4) {
      const int c0 = __builtin_nontemporal_load(col + e);
      const int c1 = __builtin_nontemporal_load(col + e + 1);
      const int c2 = __builtin_nontemporal_load(col + e + 2);
      const int c3 = __builtin_nontemporal_load(col + e + 3);
      const float v0 = __bfloat162float(hs[c0 * HIDN + f]);
      const float v1 = __bfloat162float(hs[c1 * HIDN + f]);
      const float v2 = __bfloat162float(hs[c2 * HIDN + f]);
      const float v3 = __bfloat162float(hs[c3 * HIDN + f]);
      acc += (v0 + v1) + (v2 + v3);
    }
    for (; e < re; ++e) acc += __bfloat162float(hs[col[e] * HIDN + f]);
    float v = acc * dinv[i] + bf;
    v = v > 0.f ? v : SLOPE * v;
    vrow[it * 8 + sub][f] = v;
    const int g = batch[i];
    if (g != gcur) {
      if (gcur >= 0) unsafeAtomicAdd(&pool[gcur * HIDN + f], pacc * cinv[gcur]);
      gcur = g;
      pacc = 0.f;
    }
    pacc += v;
  }
  if (gcur >= 0) unsafeAtomicAdd(&pool[gcur * HIDN + f], pacc * cinv[gcur]);

  if (FUSE) {
    __syncthreads();
#pragma unroll
    for (int q = 0; q < 4; ++q) {
      const int li = sub * 4 + q;
      const int i = base + li;
      float a = 0.f;
#pragma unroll
      for (int k = 0; k < HIDN; ++k) a += vrow[li][k] * wreg[k];
      hs_next[i * HIDN + f] = __float2bfloat16(a * dinv[i]);
    }
  }
}

// ---------------- launch ----------------

extern "C" void kernel_launch(void* const* d_in, const int* in_sizes, int n_in,
                              void* d_out, int out_size, void* d_ws, size_t ws_size,
                              hipStream_t stream) {
  const float* x = (const float*)d_in[0];
  const float* W0 = (const float*)d_in[1];
  const float* b0 = (const float*)d_in[2];
  const float* W1 = (const float*)d_in[3];
  const float* b1 = (const float*)d_in[4];
  const float* W2 = (const float*)d_in[5];
  const float* b2 = (const float*)d_in[6];
  const int* src = (const int*)d_in[7];
  const int* dst = (const int*)d_in[8];
  const int* batch = (const int*)d_in[9];
  float* out = (float*)d_out;

  char* ws = (char*)d_ws;
  auto carve = [&](size_t bytes) -> char* {
    char* p = ws;
    ws += (bytes + 255) & ~(size_t)255;
    return p;
  };
  int* deg = (int*)carve(NN * 4);
  unsigned int* rank = (unsigned int*)carve((size_t)NE);  // u8 per edge
  int* rowp = (int*)carve((NN + 1) * 4);
  int* bsum = (int*)carve(128 * 4);
  float* dinv = (float*)carve(NN * 4);
  float* cinv = (float*)carve(NG * 4);
  int* col = (int*)carve((size_t)NE * 4);
  __hip_bfloat16* hsA = (__hip_bfloat16*)carve((size_t)NN * HIDN * 2);
  __hip_bfloat16* hsB = (__hip_bfloat16*)carve((size_t)NN * HIDN * 2);

  hipMemsetAsync(deg, 0, NN * 4, stream);

  k_rank<<<SCAT_BLOCKS, 256, 0, stream>>>(dst, deg, rank);
  k_scan1<<<NBLK, 256, 0, stream>>>(deg, bsum, dinv, batch, cinv, out);
  k_scan3<<<NBLK, 256, 0, stream>>>(deg, bsum, rowp);
  k_sm<<<SCAT_BLOCKS + MM0_BLOCKS, 256, 0, stream>>>(src, dst, rank, rowp, col,
                                                     x, W0, dinv, hsA);
  // layer 0 agg (+ fused mm for layer 1)
  k_agg<1><<<AGG_BLOCKS, 256, 0, stream>>>(hsA, rowp, col, dinv, batch, cinv,
                                           b0, W1, hsB, out);
  // layer 1 agg (+ fused mm for layer 2)
  k_agg<1><<<AGG_BLOCKS, 256, 0, stream>>>(hsB, rowp, col, dinv, batch, cinv,
                                           b1, W2, hsA, out);
  // layer 2 agg (pool only)
  k_agg<0><<<AGG_BLOCKS, 256, 0, stream>>>(hsA, rowp, col, dinv, batch, cinv,
                                           b2, nullptr, nullptr, out);
}

// Round 8
// 415.692 us; speedup vs baseline: 1.1996x; 1.0572x over previous
//
#include <hip/hip_runtime.h>
#include <hip/hip_bf16.h>

#define NN 100000
#define NE 1600000
#define CIN 64
#define HIDN 32
#define NG 128
#define SLOPE 0.01f
#define NBLK 98           // (NN+1023)/1024
#define SCAT_BLOCKS 782   // ceil(NE/8/256)
#define MM0_BLOCKS 12500  // NN*HIDN/256
#define AGG_BLOCKS 3125   // NN/32

// ---------------- CSR build: one atomic pass producing u8 ranks ----------------

__global__ __launch_bounds__(256) void k_rank(const int* __restrict__ dst,
                                              int* __restrict__ deg,
                                              unsigned int* __restrict__ rank) {
  int i = blockIdx.x * 256 + threadIdx.x;  // oct-edge index
  if (i * 8 >= NE) return;
  int4 a = ((const int4*)dst)[2 * i];
  int4 b = ((const int4*)dst)[2 * i + 1];
  unsigned int r0 = atomicAdd(&deg[a.x], 1);
  unsigned int r1 = atomicAdd(&deg[a.y], 1);
  unsigned int r2 = atomicAdd(&deg[a.z], 1);
  unsigned int r3 = atomicAdd(&deg[a.w], 1);
  unsigned int r4 = atomicAdd(&deg[b.x], 1);
  unsigned int r5 = atomicAdd(&deg[b.y], 1);
  unsigned int r6 = atomicAdd(&deg[b.z], 1);
  unsigned int r7 = atomicAdd(&deg[b.w], 1);
  uint2 packed;
  packed.x = r0 | (r1 << 8) | (r2 << 16) | (r3 << 24);
  packed.y = r4 | (r5 << 8) | (r6 << 16) | (r7 << 24);
  ((uint2*)rank)[i] = packed;
}

// ---------------- scan1: block sums + dinv; block 0 also cinv + zero out ----------------

__global__ __launch_bounds__(256) void k_scan1(const int* __restrict__ deg,
                                               int* __restrict__ bsum,
                                               float* __restrict__ dinv,
                                               const int* __restrict__ batch,
                                               float* __restrict__ cinv,
                                               float* __restrict__ out) {
  __shared__ int s[256];
  __shared__ int sb[NG + 1];
  int t = threadIdx.x;
  int base = blockIdx.x * 1024 + t * 4;
  int sum = 0;
#pragma unroll
  for (int j = 0; j < 4; ++j) {
    int idx = base + j;
    if (idx < NN) {
      int d = deg[idx];
      sum += d;
      dinv[idx] = rsqrtf((float)d + 1.0f);
    }
  }
  s[t] = sum;
  __syncthreads();
  for (int o = 128; o > 0; o >>= 1) {
    if (t < o) s[t] += s[t + o];
    __syncthreads();
  }
  if (t == 0) bsum[blockIdx.x] = s[0];
  if (blockIdx.x == 0) {
    if (t <= NG) {
      int lo = 0, hi = NN;  // lower_bound of t in sorted batch
      while (lo < hi) {
        int mid = (lo + hi) >> 1;
        if (batch[mid] < t) lo = mid + 1; else hi = mid;
      }
      sb[t] = lo;
    }
    for (int i = t; i < NG * HIDN; i += 256) out[i] = 0.f;
    __syncthreads();
    if (t < NG) {
      int c = sb[t + 1] - sb[t];
      cinv[t] = 1.0f / (3.0f * fmaxf((float)c, 1.0f));
    }
  }
}

// ---------------- scan3: self-scan block sums + per-element rowp ----------------

__global__ __launch_bounds__(256) void k_scan3(const int* __restrict__ deg,
                                               const int* __restrict__ bsum,
                                               int* __restrict__ rowp) {
  __shared__ int s[256];
  __shared__ int sb2[128];
  int t = threadIdx.x;
  if (t < 128) sb2[t] = (t < NBLK) ? bsum[t] : 0;
  int base = blockIdx.x * 1024 + t * 4;
  int d0 = 0, d1 = 0, d2 = 0, d3 = 0;
  if (base < NN) d0 = deg[base];
  if (base + 1 < NN) d1 = deg[base + 1];
  if (base + 2 < NN) d2 = deg[base + 2];
  if (base + 3 < NN) d3 = deg[base + 3];
  int ts = d0 + d1 + d2 + d3;
  s[t] = ts;
  __syncthreads();
  // inclusive scan of the 98 block sums (128-wide Hillis)
  for (int o = 1; o < 128; o <<= 1) {
    int v = (t < 128 && t >= o) ? sb2[t - o] : 0;
    __syncthreads();
    if (t < 128) sb2[t] += v;
    __syncthreads();
  }
  // inclusive scan of the 256 thread sums
  for (int o = 1; o < 256; o <<= 1) {
    int v = (t >= o) ? s[t - o] : 0;
    __syncthreads();
    s[t] += v;
    __syncthreads();
  }
  int blockoff = blockIdx.x ? sb2[blockIdx.x - 1] : 0;
  int run = blockoff + s[t] - ts;  // exclusive prefix
  if (base < NN) { rowp[base] = run; run += d0; }
  if (base + 1 < NN) { rowp[base + 1] = run; run += d1; }
  if (base + 2 < NN) { rowp[base + 2] = run; run += d2; }
  if (base + 3 < NN) { rowp[base + 3] = run; run += d3; }
  if (blockIdx.x == NBLK - 1 && t == 255) rowp[NN] = run;  // == NE
}

// ---------------- scatter (blocks 0..781)  ∥  mm0 (blocks 782..) ----------------

__global__ __launch_bounds__(256) void k_sm(const int* __restrict__ src,
                                            const int* __restrict__ dst,
                                            const unsigned int* __restrict__ rank,
                                            const int* __restrict__ rowp,
                                            int* __restrict__ col,
                                            const float* __restrict__ x,
                                            const float* __restrict__ W0,
                                            const float* __restrict__ dinv,
                                            __hip_bfloat16* __restrict__ hs) {
  __shared__ float sW[CIN * HIDN];
  if (blockIdx.x < SCAT_BLOCKS) {
    int i = blockIdx.x * 256 + threadIdx.x;  // oct-edge index
    if (i * 8 >= NE) return;
    int4 da = ((const int4*)dst)[2 * i];
    int4 db = ((const int4*)dst)[2 * i + 1];
    uint2 rr = ((const uint2*)rank)[i];
    int4 sa = ((const int4*)src)[2 * i];
    int4 sb = ((const int4*)src)[2 * i + 1];
    col[rowp[da.x] + (int)(rr.x & 0xff)] = sa.x;
    col[rowp[da.y] + (int)((rr.x >> 8) & 0xff)] = sa.y;
    col[rowp[da.z] + (int)((rr.x >> 16) & 0xff)] = sa.z;
    col[rowp[da.w] + (int)(rr.x >> 24)] = sa.w;
    col[rowp[db.x] + (int)(rr.y & 0xff)] = sb.x;
    col[rowp[db.y] + (int)((rr.y >> 8) & 0xff)] = sb.y;
    col[rowp[db.z] + (int)((rr.y >> 16) & 0xff)] = sb.z;
    col[rowp[db.w] + (int)(rr.y >> 24)] = sb.w;
    return;
  }
  int t = threadIdx.x;
  for (int i = t; i < CIN * HIDN; i += 256) sW[i] = W0[i];
  __syncthreads();
  int gid = (blockIdx.x - SCAT_BLOCKS) * 256 + t;
  int node = gid >> 5;
  int f = gid & 31;
  const float* xr = x + node * CIN;
  float acc = 0.f;
#pragma unroll
  for (int k = 0; k < CIN; ++k) acc += xr[k] * sW[k * HIDN + f];
  hs[node * HIDN + f] = __float2bfloat16(acc * dinv[node]);
}

// ---------------- CSR aggregation + epilogue (+ optional fused next-layer mm) ----------------
// Round-5 per-row gather structure (proven 66us). hs pre-scaled by dinv.
// FUSE: stage v rows + Wn in LDS (NOT registers: keeps gather-phase VGPR low,
// occupancy high), then hs_next = bf16(dinv * (v @ Wn)).

template <int FUSE>
__global__ __launch_bounds__(256) void k_agg(const __hip_bfloat16* __restrict__ hs,
                                             const int* __restrict__ rowp,
                                             const int* __restrict__ col,
                                             const float* __restrict__ dinv,
                                             const int* __restrict__ batch,
                                             const float* __restrict__ cinv,
                                             const float* __restrict__ bias,
                                             const float* __restrict__ Wn,
                                             __hip_bfloat16* __restrict__ hs_next,
                                             float* __restrict__ pool) {
  __shared__ float vrow[32][32];
  __shared__ float sWn[FUSE ? HIDN * HIDN : 1];
  const int t = threadIdx.x;
  const int f = t & 31;
  const int sub = t >> 5;  // 0..7
  const int base = blockIdx.x * 32;

  if (FUSE) {
#pragma unroll
    for (int i = 0; i < 4; ++i) sWn[t + i * 256] = Wn[t + i * 256];
  }

  const float bf = bias[f];
  float pacc = 0.f;
  int gcur = -1;
#pragma unroll
  for (int it = 0; it < 4; ++it) {
    const int i = base + it * 8 + sub;  // always < NN (NN % 32 == 0)
    float acc = __bfloat162float(hs[i * HIDN + f]);  // self-loop term
    const int rs = rowp[i];
    const int re = rowp[i + 1];
    int e = rs;
    for (; e + 8 <= re; e += 8) {
      const int c0 = __builtin_nontemporal_load(col + e);
      const int c1 = __builtin_nontemporal_load(col + e + 1);
      const int c2 = __builtin_nontemporal_load(col + e + 2);
      const int c3 = __builtin_nontemporal_load(col + e + 3);
      const int c4 = __builtin_nontemporal_load(col + e + 4);
      const int c5 = __builtin_nontemporal_load(col + e + 5);
      const int c6 = __builtin_nontemporal_load(col + e + 6);
      const int c7 = __builtin_nontemporal_load(col + e + 7);
      const float v0 = __bfloat162float(hs[c0 * HIDN + f]);
      const float v1 = __bfloat162float(hs[c1 * HIDN + f]);
      const float v2 = __bfloat162float(hs[c2 * HIDN + f]);
      const float v3 = __bfloat162float(hs[c3 * HIDN + f]);
      const float v4 = __bfloat162float(hs[c4 * HIDN + f]);
      const float v5 = __bfloat162float(hs[c5 * HIDN + f]);
      const float v6 = __bfloat162float(hs[c6 * HIDN + f]);
      const float v7 = __bfloat162float(hs[c7 * HIDN + f]);
      acc += ((v0 + v1) + (v2 + v3)) + ((v4 + v5) + (v6 + v7));
    }
    for (; e + 4 <= re; e += 4) {
      const int c0 = __builtin_nontemporal_load(col + e);
      const int c1 = __builtin_nontemporal_load(col + e + 1);
      const int c2 = __builtin_nontemporal_load(col + e + 2);
      const int c3 = __builtin_nontemporal_load(col + e + 3);
      const float v0 = __bfloat162float(hs[c0 * HIDN + f]);
      const float v1 = __bfloat162float(hs[c1 * HIDN + f]);
      const float v2 = __bfloat162float(hs[c2 * HIDN + f]);
      const float v3 = __bfloat162float(hs[c3 * HIDN + f]);
      acc += (v0 + v1) + (v2 + v3);
    }
    for (; e < re; ++e) acc += __bfloat162float(hs[col[e] * HIDN + f]);
    float v = acc * dinv[i] + bf;
    v = v > 0.f ? v : SLOPE * v;
    if (FUSE) vrow[it * 8 + sub][f] = v;
    const int g = batch[i];
    if (g != gcur) {
      if (gcur >= 0) unsafeAtomicAdd(&pool[gcur * HIDN + f], pacc * cinv[gcur]);
      gcur = g;
      pacc = 0.f;
    }
    pacc += v;
  }
  if (gcur >= 0) unsafeAtomicAdd(&pool[gcur * HIDN + f], pacc * cinv[gcur]);

  if (FUSE) {
    __syncthreads();
#pragma unroll
    for (int q = 0; q < 4; ++q) {
      const int li = sub * 4 + q;
      const int i = base + li;
      float a = 0.f;
#pragma unroll
      for (int k = 0; k < HIDN; ++k) a += vrow[li][k] * sWn[k * HIDN + f];
      hs_next[i * HIDN + f] = __float2bfloat16(a * dinv[i]);
    }
  }
}

// ---------------- launch ----------------

extern "C" void kernel_launch(void* const* d_in, const int* in_sizes, int n_in,
                              void* d_out, int out_size, void* d_ws, size_t ws_size,
                              hipStream_t stream) {
  const float* x = (const float*)d_in[0];
  const float* W0 = (const float*)d_in[1];
  const float* b0 = (const float*)d_in[2];
  const float* W1 = (const float*)d_in[3];
  const float* b1 = (const float*)d_in[4];
  const float* W2 = (const float*)d_in[5];
  const float* b2 = (const float*)d_in[6];
  const int* src = (const int*)d_in[7];
  const int* dst = (const int*)d_in[8];
  const int* batch = (const int*)d_in[9];
  float* out = (float*)d_out;

  char* ws = (char*)d_ws;
  auto carve = [&](size_t bytes) -> char* {
    char* p = ws;
    ws += (bytes + 255) & ~(size_t)255;
    return p;
  };
  int* deg = (int*)carve(NN * 4);
  unsigned int* rank = (unsigned int*)carve((size_t)NE);  // u8 per edge
  int* rowp = (int*)carve((NN + 1) * 4);
  int* bsum = (int*)carve(128 * 4);
  float* dinv = (float*)carve(NN * 4);
  float* cinv = (float*)carve(NG * 4);
  int* col = (int*)carve((size_t)NE * 4);
  __hip_bfloat16* hsA = (__hip_bfloat16*)carve((size_t)NN * HIDN * 2);
  __hip_bfloat16* hsB = (__hip_bfloat16*)carve((size_t)NN * HIDN * 2);

  hipMemsetAsync(deg, 0, NN * 4, stream);

  k_rank<<<SCAT_BLOCKS, 256, 0, stream>>>(dst, deg, rank);
  k_scan1<<<NBLK, 256, 0, stream>>>(deg, bsum, dinv, batch, cinv, out);
  k_scan3<<<NBLK, 256, 0, stream>>>(deg, bsum, rowp);
  k_sm<<<SCAT_BLOCKS + MM0_BLOCKS, 256, 0, stream>>>(src, dst, rank, rowp, col,
                                                     x, W0, dinv, hsA);
  // layer 0 agg (+ fused mm for layer 1)
  k_agg<1><<<AGG_BLOCKS, 256, 0, stream>>>(hsA, rowp, col, dinv, batch, cinv,
                                           b0, W1, hsB, out);
  // layer 1 agg (+ fused mm for layer 2)
  k_agg<1><<<AGG_BLOCKS, 256, 0, stream>>>(hsB, rowp, col, dinv, batch, cinv,
                                           b1, W2, hsA, out);
  // layer 2 agg (pool only)
  k_agg<0><<<AGG_BLOCKS, 256, 0, stream>>>(hsA, rowp, col, dinv, batch, cinv,
                                           b2, nullptr, nullptr, out);
}

// Round 9
// 414.162 us; speedup vs baseline: 1.2040x; 1.0037x over previous
//
#include <hip/hip_runtime.h>
#include <hip/hip_bf16.h>

#define NN 100000
#define NE 1600000
#define CIN 64
#define HIDN 32
#define NG 128
#define SLOPE 0.01f
#define NBLK 98           // (NN+1023)/1024
#define SCAT_BLOCKS 782   // ceil(NE/8/256)
#define MM0_BLOCKS 12500  // NN*HIDN/256
#define AGG_BLOCKS 3125   // NN/32
#define SCAN_RDY 0x40000000u

// ---------------- CSR build: one atomic pass producing u8 ranks ----------------

__global__ __launch_bounds__(256) void k_rank(const int* __restrict__ dst,
                                              int* __restrict__ deg,
                                              unsigned int* __restrict__ rank) {
  int i = blockIdx.x * 256 + threadIdx.x;  // oct-edge index
  if (i * 8 >= NE) return;
  int4 a = ((const int4*)dst)[2 * i];
  int4 b = ((const int4*)dst)[2 * i + 1];
  unsigned int r0 = atomicAdd(&deg[a.x], 1);
  unsigned int r1 = atomicAdd(&deg[a.y], 1);
  unsigned int r2 = atomicAdd(&deg[a.z], 1);
  unsigned int r3 = atomicAdd(&deg[a.w], 1);
  unsigned int r4 = atomicAdd(&deg[b.x], 1);
  unsigned int r5 = atomicAdd(&deg[b.y], 1);
  unsigned int r6 = atomicAdd(&deg[b.z], 1);
  unsigned int r7 = atomicAdd(&deg[b.w], 1);
  uint2 packed;
  packed.x = r0 | (r1 << 8) | (r2 << 16) | (r3 << 24);
  packed.y = r4 | (r5 << 8) | (r6 << 16) | (r7 << 24);
  ((uint2*)rank)[i] = packed;
}

// ---------------- single-pass scan (decoupled lookback) + dinv + cinv + out-zero ----
// 98 blocks <= #CUs: all co-resident, so spinning on earlier blocks' flags is safe.
// flagA[b] = block aggregate | RDY; flagP[b] = inclusive prefix | RDY. Zeroed by host memset.

__global__ __launch_bounds__(256) void k_scan(const int* __restrict__ deg,
                                              int* __restrict__ rowp,
                                              float* __restrict__ dinv,
                                              const int* __restrict__ batch,
                                              float* __restrict__ cinv,
                                              float* __restrict__ out,
                                              unsigned int* __restrict__ flagA,
                                              unsigned int* __restrict__ flagP) {
  __shared__ int s[256];
  __shared__ int sboff;
  __shared__ int sb[NG + 1];
  const int t = threadIdx.x;
  const int b = blockIdx.x;
  const int base = b * 1024 + t * 4;
  int d0 = 0, d1 = 0, d2 = 0, d3 = 0;
  if (base < NN) { d0 = deg[base]; dinv[base] = rsqrtf((float)d0 + 1.0f); }
  if (base + 1 < NN) { d1 = deg[base + 1]; dinv[base + 1] = rsqrtf((float)d1 + 1.0f); }
  if (base + 2 < NN) { d2 = deg[base + 2]; dinv[base + 2] = rsqrtf((float)d2 + 1.0f); }
  if (base + 3 < NN) { d3 = deg[base + 3]; dinv[base + 3] = rsqrtf((float)d3 + 1.0f); }
  const int ts = d0 + d1 + d2 + d3;
  s[t] = ts;
  __syncthreads();
  for (int o = 1; o < 256; o <<= 1) {
    int v = (t >= o) ? s[t - o] : 0;
    __syncthreads();
    s[t] += v;
    __syncthreads();
  }
  const int total = s[255];
  if (t == 0) {
    __threadfence();
    atomicExch(&flagA[b], (unsigned)total | SCAN_RDY);
    unsigned run = 0;
    if (b > 0) {
      int j = b - 1;
      while (j >= 0) {
        unsigned p = atomicAdd(&flagP[j], 0u);
        if (p & SCAN_RDY) { run += p & 0x3FFFFFFFu; break; }
        unsigned a = atomicAdd(&flagA[j], 0u);
        if (a & SCAN_RDY) { run += a & 0x3FFFFFFFu; --j; }
      }
    }
    __threadfence();
    atomicExch(&flagP[b], (run + (unsigned)total) | SCAN_RDY);
    sboff = (int)run;
  }
  __syncthreads();
  int run = sboff + s[t] - ts;  // exclusive prefix for this thread
  if (base < NN) { rowp[base] = run; run += d0; }
  if (base + 1 < NN) { rowp[base + 1] = run; run += d1; }
  if (base + 2 < NN) { rowp[base + 2] = run; run += d2; }
  if (base + 3 < NN) { rowp[base + 3] = run; run += d3; }
  if (b == NBLK - 1 && t == 255) rowp[NN] = run;  // == NE

  if (b == 0) {  // cinv + zero out (independent of scan)
    if (t <= NG) {
      int lo = 0, hi = NN;  // lower_bound of t in sorted batch
      while (lo < hi) {
        int mid = (lo + hi) >> 1;
        if (batch[mid] < t) lo = mid + 1; else hi = mid;
      }
      sb[t] = lo;
    }
    for (int i = t; i < NG * HIDN; i += 256) out[i] = 0.f;
    __syncthreads();
    if (t < NG) {
      int c = sb[t + 1] - sb[t];
      cinv[t] = 1.0f / (3.0f * fmaxf((float)c, 1.0f));
    }
  }
}

// ---------------- scatter (blocks 0..781)  ∥  mm0 (blocks 782..) ----------------

__global__ __launch_bounds__(256) void k_sm(const int* __restrict__ src,
                                            const int* __restrict__ dst,
                                            const unsigned int* __restrict__ rank,
                                            const int* __restrict__ rowp,
                                            int* __restrict__ col,
                                            const float* __restrict__ x,
                                            const float* __restrict__ W0,
                                            const float* __restrict__ dinv,
                                            __hip_bfloat16* __restrict__ hs) {
  __shared__ float sW[CIN * HIDN];
  if (blockIdx.x < SCAT_BLOCKS) {
    int i = blockIdx.x * 256 + threadIdx.x;  // oct-edge index
    if (i * 8 >= NE) return;
    int4 da = ((const int4*)dst)[2 * i];
    int4 db = ((const int4*)dst)[2 * i + 1];
    uint2 rr = ((const uint2*)rank)[i];
    int4 sa = ((const int4*)src)[2 * i];
    int4 sb = ((const int4*)src)[2 * i + 1];
    col[rowp[da.x] + (int)(rr.x & 0xff)] = sa.x;
    col[rowp[da.y] + (int)((rr.x >> 8) & 0xff)] = sa.y;
    col[rowp[da.z] + (int)((rr.x >> 16) & 0xff)] = sa.z;
    col[rowp[da.w] + (int)(rr.x >> 24)] = sa.w;
    col[rowp[db.x] + (int)(rr.y & 0xff)] = sb.x;
    col[rowp[db.y] + (int)((rr.y >> 8) & 0xff)] = sb.y;
    col[rowp[db.z] + (int)((rr.y >> 16) & 0xff)] = sb.z;
    col[rowp[db.w] + (int)(rr.y >> 24)] = sb.w;
    return;
  }
  int t = threadIdx.x;
  for (int i = t; i < CIN * HIDN; i += 256) sW[i] = W0[i];
  __syncthreads();
  int gid = (blockIdx.x - SCAT_BLOCKS) * 256 + t;
  int node = gid >> 5;
  int f = gid & 31;
  const float* xr = x + node * CIN;
  float acc = 0.f;
#pragma unroll
  for (int k = 0; k < CIN; ++k) acc += xr[k] * sW[k * HIDN + f];
  hs[node * HIDN + f] = __float2bfloat16(acc * dinv[node]);
}

// ---------------- CSR aggregation + epilogue (+ optional fused next-layer mm) ----------------
// hs pre-scaled by dinv. Col loads software-pipelined: next batch's col loads issue
// while current batch's gathers are in flight (removes col latency from critical path).

template <int FUSE>
__global__ __launch_bounds__(256) void k_agg(const __hip_bfloat16* __restrict__ hs,
                                             const int* __restrict__ rowp,
                                             const int* __restrict__ col,
                                             const float* __restrict__ dinv,
                                             const int* __restrict__ batch,
                                             const float* __restrict__ cinv,
                                             const float* __restrict__ bias,
                                             const float* __restrict__ Wn,
                                             __hip_bfloat16* __restrict__ hs_next,
                                             float* __restrict__ pool) {
  __shared__ float vrow[32][32];
  __shared__ float sWn[FUSE ? HIDN * HIDN : 1];
  const int t = threadIdx.x;
  const int f = t & 31;
  const int sub = t >> 5;  // 0..7
  const int base = blockIdx.x * 32;

  if (FUSE) {
#pragma unroll
    for (int i = 0; i < 4; ++i) sWn[t + i * 256] = Wn[t + i * 256];
  }

  const float bf = bias[f];
  float pacc = 0.f;
  int gcur = -1;
#pragma unroll
  for (int it = 0; it < 4; ++it) {
    const int i = base + it * 8 + sub;  // always < NN (NN % 32 == 0)
    float acc = __bfloat162float(hs[i * HIDN + f]);  // self-loop term
    const int rs = rowp[i];
    const int re = rowp[i + 1];
    int e = rs;
    const int nfull = (re - rs) >> 3;
    if (nfull > 0) {
      int c0 = __builtin_nontemporal_load(col + e);
      int c1 = __builtin_nontemporal_load(col + e + 1);
      int c2 = __builtin_nontemporal_load(col + e + 2);
      int c3 = __builtin_nontemporal_load(col + e + 3);
      int c4 = __builtin_nontemporal_load(col + e + 4);
      int c5 = __builtin_nontemporal_load(col + e + 5);
      int c6 = __builtin_nontemporal_load(col + e + 6);
      int c7 = __builtin_nontemporal_load(col + e + 7);
      for (int bi = 1; bi < nfull; ++bi) {
        const int n0 = __builtin_nontemporal_load(col + e + 8);
        const int n1 = __builtin_nontemporal_load(col + e + 9);
        const int n2 = __builtin_nontemporal_load(col + e + 10);
        const int n3 = __builtin_nontemporal_load(col + e + 11);
        const int n4 = __builtin_nontemporal_load(col + e + 12);
        const int n5 = __builtin_nontemporal_load(col + e + 13);
        const int n6 = __builtin_nontemporal_load(col + e + 14);
        const int n7 = __builtin_nontemporal_load(col + e + 15);
        const float v0 = __bfloat162float(hs[c0 * HIDN + f]);
        const float v1 = __bfloat162float(hs[c1 * HIDN + f]);
        const float v2 = __bfloat162float(hs[c2 * HIDN + f]);
        const float v3 = __bfloat162float(hs[c3 * HIDN + f]);
        const float v4 = __bfloat162float(hs[c4 * HIDN + f]);
        const float v5 = __bfloat162float(hs[c5 * HIDN + f]);
        const float v6 = __bfloat162float(hs[c6 * HIDN + f]);
        const float v7 = __bfloat162float(hs[c7 * HIDN + f]);
        acc += ((v0 + v1) + (v2 + v3)) + ((v4 + v5) + (v6 + v7));
        c0 = n0; c1 = n1; c2 = n2; c3 = n3; c4 = n4; c5 = n5; c6 = n6; c7 = n7;
        e += 8;
      }
      const float v0 = __bfloat162float(hs[c0 * HIDN + f]);
      const float v1 = __bfloat162float(hs[c1 * HIDN + f]);
      const float v2 = __bfloat162float(hs[c2 * HIDN + f]);
      const float v3 = __bfloat162float(hs[c3 * HIDN + f]);
      const float v4 = __bfloat162float(hs[c4 * HIDN + f]);
      const float v5 = __bfloat162float(hs[c5 * HIDN + f]);
      const float v6 = __bfloat162float(hs[c6 * HIDN + f]);
      const float v7 = __bfloat162float(hs[c7 * HIDN + f]);
      acc += ((v0 + v1) + (v2 + v3)) + ((v4 + v5) + (v6 + v7));
      e += 8;
    }
    if (re - e >= 4) {
      const int c0 = __builtin_nontemporal_load(col + e);
      const int c1 = __builtin_nontemporal_load(col + e + 1);
      const int c2 = __builtin_nontemporal_load(col + e + 2);
      const int c3 = __builtin_nontemporal_load(col + e + 3);
      const float v0 = __bfloat162float(hs[c0 * HIDN + f]);
      const float v1 = __bfloat162float(hs[c1 * HIDN + f]);
      const float v2 = __bfloat162float(hs[c2 * HIDN + f]);
      const float v3 = __bfloat162float(hs[c3 * HIDN + f]);
      acc += (v0 + v1) + (v2 + v3);
      e += 4;
    }
    for (; e < re; ++e) acc += __bfloat162float(hs[col[e] * HIDN + f]);
    float v = acc * dinv[i] + bf;
    v = v > 0.f ? v : SLOPE * v;
    if (FUSE) vrow[it * 8 + sub][f] = v;
    const int g = batch[i];
    if (g != gcur) {
      if (gcur >= 0) unsafeAtomicAdd(&pool[gcur * HIDN + f], pacc * cinv[gcur]);
      gcur = g;
      pacc = 0.f;
    }
    pacc += v;
  }
  if (gcur >= 0) unsafeAtomicAdd(&pool[gcur * HIDN + f], pacc * cinv[gcur]);

  if (FUSE) {
    __syncthreads();
#pragma unroll
    for (int q = 0; q < 4; ++q) {
      const int li = sub * 4 + q;
      const int i = base + li;
      float a = 0.f;
#pragma unroll
      for (int k = 0; k < HIDN; ++k) a += vrow[li][k] * sWn[k * HIDN + f];
      hs_next[i * HIDN + f] = __float2bfloat16(a * dinv[i]);
    }
  }
}

// ---------------- launch ----------------

extern "C" void kernel_launch(void* const* d_in, const int* in_sizes, int n_in,
                              void* d_out, int out_size, void* d_ws, size_t ws_size,
                              hipStream_t stream) {
  const float* x = (const float*)d_in[0];
  const float* W0 = (const float*)d_in[1];
  const float* b0 = (const float*)d_in[2];
  const float* W1 = (const float*)d_in[3];
  const float* b1 = (const float*)d_in[4];
  const float* W2 = (const float*)d_in[5];
  const float* b2 = (const float*)d_in[6];
  const int* src = (const int*)d_in[7];
  const int* dst = (const int*)d_in[8];
  const int* batch = (const int*)d_in[9];
  float* out = (float*)d_out;

  char* ws = (char*)d_ws;
  auto carve = [&](size_t bytes) -> char* {
    char* p = ws;
    ws += (bytes + 255) & ~(size_t)255;
    return p;
  };
  // flags + deg contiguous -> single memset zeroes all three
  unsigned int* flagA = (unsigned int*)carve(512);
  unsigned int* flagP = (unsigned int*)carve(512);
  int* deg = (int*)carve(NN * 4);
  unsigned int* rank = (unsigned int*)carve((size_t)NE);  // u8 per edge
  int* rowp = (int*)carve((NN + 1) * 4);
  float* dinv = (float*)carve(NN * 4);
  float* cinv = (float*)carve(NG * 4);
  int* col = (int*)carve((size_t)NE * 4);
  __hip_bfloat16* hsA = (__hip_bfloat16*)carve((size_t)NN * HIDN * 2);
  __hip_bfloat16* hsB = (__hip_bfloat16*)carve((size_t)NN * HIDN * 2);

  hipMemsetAsync(flagA, 0, 1024 + ((NN * 4 + 255) & ~255), stream);

  k_rank<<<SCAT_BLOCKS, 256, 0, stream>>>(dst, deg, rank);
  k_scan<<<NBLK, 256, 0, stream>>>(deg, rowp, dinv, batch, cinv, out, flagA, flagP);
  k_sm<<<SCAT_BLOCKS + MM0_BLOCKS, 256, 0, stream>>>(src, dst, rank, rowp, col,
                                                     x, W0, dinv, hsA);
  // layer 0 agg (+ fused mm for layer 1)
  k_agg<1><<<AGG_BLOCKS, 256, 0, stream>>>(hsA, rowp, col, dinv, batch, cinv,
                                           b0, W1, hsB, out);
  // layer 1 agg (+ fused mm for layer 2)
  k_agg<1><<<AGG_BLOCKS, 256, 0, stream>>>(hsB, rowp, col, dinv, batch, cinv,
                                           b1, W2, hsA, out);
  // layer 2 agg (pool only)
  k_agg<0><<<AGG_BLOCKS, 256, 0, stream>>>(hsA, rowp, col, dinv, batch, cinv,
                                           b2, nullptr, nullptr, out);
}